// Round 2
// baseline (992.500 us; speedup 1.0000x reference)
//
#include <hip/hip_runtime.h>
#include <hip/hip_bf16.h>
#include <math.h>

#define D_EMBED 512
#define NUM_HEADS 8
#define HEAD_DIM 64
#define D_FF 2048
#define BATCH 2
#define SEQ 4096
#define M_ROWS (BATCH*SEQ)   // 8192

typedef __attribute__((ext_vector_type(8))) short short8;
typedef __attribute__((ext_vector_type(4))) short short4_t;
typedef __attribute__((ext_vector_type(4))) float f32x4;

#if __has_builtin(__builtin_amdgcn_mfma_f32_16x16x16bf16_1k)
#define MFMA_K16(a,b,c) __builtin_amdgcn_mfma_f32_16x16x16bf16_1k(a,b,c,0,0,0)
#define HAVE_MFMA_K16 1
#elif __has_builtin(__builtin_amdgcn_mfma_f32_16x16x16_bf16)
#define MFMA_K16(a,b,c) __builtin_amdgcn_mfma_f32_16x16x16_bf16(a,b,c,0,0,0)
#define HAVE_MFMA_K16 1
#else
#define HAVE_MFMA_K16 0
#endif

__device__ inline unsigned short f2b(float f) {
    union { float f; unsigned u; } v; v.f = f;
    unsigned r = v.u + 0x7fffu + ((v.u >> 16) & 1u);
    return (unsigned short)(r >> 16);
}

__device__ inline void gl2lds16(const void* g, void* l) {
    __builtin_amdgcn_global_load_lds(
        (const __attribute__((address_space(1))) unsigned int*)g,
        (__attribute__((address_space(3))) unsigned int*)l, 16, 0, 0);
}

// ---------------------------------------------------------------------------
// GEMM 128x128: C[M][N] = A[M][K](bf16) * BT[N][K](bf16)^T + bias
// EPI 0: bf16; EPI 1: fp32; EPI 2: GELU->bf16. Cols < scale_cols get *0.125.
// ---------------------------------------------------------------------------
template<int EPI>
__global__ __launch_bounds__(256) void gemm_bt(
    const unsigned short* __restrict__ A, const unsigned short* __restrict__ BT,
    const float* __restrict__ bias, void* __restrict__ Cout,
    int M, int N, int K, int scale_cols)
{
    __shared__ __align__(16) unsigned short As[128*32];
    __shared__ __align__(16) unsigned short Bs[128*32];
    const int tid  = threadIdx.x;
    const int wave = tid >> 6, lane = tid & 63;
    const int wy = wave >> 1, wx = wave & 1;
    const int quad = lane >> 4, m16 = lane & 15;
    const int row0 = blockIdx.y * 128, n0 = blockIdx.x * 128;

    f32x4 acc[4][4];
#pragma unroll
    for (int i = 0; i < 4; i++)
#pragma unroll
        for (int j = 0; j < 4; j++) acc[i][j] = (f32x4){0.f,0.f,0.f,0.f};

    const int kIters = K >> 5;
    for (int kt = 0; kt < kIters; ++kt) {
        const int k0 = kt << 5;
#pragma unroll
        for (int it = 0; it < 2; ++it) {
            int g  = it*256 + tid;
            int r  = g >> 2, c8 = (g & 3) << 3;
            gl2lds16(A  + (size_t)(row0 + r)*K + k0 + c8, &As[(size_t)(it*256 + wave*64)*8]);
            gl2lds16(BT + (size_t)(n0  + r)*K + k0 + c8, &Bs[(size_t)(it*256 + wave*64)*8]);
        }
        __syncthreads();
        short8 a[4], b[4];
#pragma unroll
        for (int i = 0; i < 4; i++) a[i] = *(const short8*)&As[(wy*64 + i*16 + m16)*32 + quad*8];
#pragma unroll
        for (int j = 0; j < 4; j++) b[j] = *(const short8*)&Bs[(wx*64 + j*16 + m16)*32 + quad*8];
#pragma unroll
        for (int i = 0; i < 4; i++)
#pragma unroll
            for (int j = 0; j < 4; j++)
                acc[i][j] = __builtin_amdgcn_mfma_f32_16x16x32_bf16(a[i], b[j], acc[i][j], 0, 0, 0);
        __syncthreads();
    }

#pragma unroll
    for (int j = 0; j < 4; j++) {
        int col = n0 + wx*64 + j*16 + m16;
        float bj = bias[col];
        float sc = (col < scale_cols) ? 0.125f : 1.0f;
#pragma unroll
        for (int i = 0; i < 4; i++) {
            int rbase = row0 + wy*64 + i*16 + quad*4;
#pragma unroll
            for (int r = 0; r < 4; r++) {
                float v = (acc[i][j][r] + bj) * sc;
                size_t idx = (size_t)(rbase + r)*N + col;
                if (EPI == 0) {
                    ((unsigned short*)Cout)[idx] = f2b(v);
                } else if (EPI == 1) {
                    ((float*)Cout)[idx] = v;
                } else {
                    float gv = 0.5f * v * (1.0f + erff(v * 0.70710678118654752f));
                    ((unsigned short*)Cout)[idx] = f2b(gv);
                }
            }
        }
    }
}

// ---------------------------------------------------------------------------
// GEMM 64x128 tile (for N=512 matmuls: doubles grid to 512 blocks = 2/CU)
// ---------------------------------------------------------------------------
template<int EPI>
__global__ __launch_bounds__(256) void gemm_bt64(
    const unsigned short* __restrict__ A, const unsigned short* __restrict__ BT,
    const float* __restrict__ bias, void* __restrict__ Cout,
    int M, int N, int K, int scale_cols)
{
    __shared__ __align__(16) unsigned short As[64*32];
    __shared__ __align__(16) unsigned short Bs[128*32];
    const int tid  = threadIdx.x;
    const int wave = tid >> 6, lane = tid & 63;
    const int wy = wave >> 1, wx = wave & 1;
    const int quad = lane >> 4, m16 = lane & 15;
    const int row0 = blockIdx.y * 64, n0 = blockIdx.x * 128;

    f32x4 acc[2][4];
#pragma unroll
    for (int i = 0; i < 2; i++)
#pragma unroll
        for (int j = 0; j < 4; j++) acc[i][j] = (f32x4){0.f,0.f,0.f,0.f};

    const int kIters = K >> 5;
    for (int kt = 0; kt < kIters; ++kt) {
        const int k0 = kt << 5;
        {
            int r = tid >> 2, c8 = (tid & 3) << 3;
            gl2lds16(A + (size_t)(row0 + r)*K + k0 + c8, &As[(size_t)(wave*64)*8]);
        }
#pragma unroll
        for (int it = 0; it < 2; ++it) {
            int g  = it*256 + tid;
            int r  = g >> 2, c8 = (g & 3) << 3;
            gl2lds16(BT + (size_t)(n0 + r)*K + k0 + c8, &Bs[(size_t)(it*256 + wave*64)*8]);
        }
        __syncthreads();
        short8 a[2], b[4];
#pragma unroll
        for (int i = 0; i < 2; i++) a[i] = *(const short8*)&As[(wy*32 + i*16 + m16)*32 + quad*8];
#pragma unroll
        for (int j = 0; j < 4; j++) b[j] = *(const short8*)&Bs[(wx*64 + j*16 + m16)*32 + quad*8];
#pragma unroll
        for (int i = 0; i < 2; i++)
#pragma unroll
            for (int j = 0; j < 4; j++)
                acc[i][j] = __builtin_amdgcn_mfma_f32_16x16x32_bf16(a[i], b[j], acc[i][j], 0, 0, 0);
        __syncthreads();
    }

#pragma unroll
    for (int j = 0; j < 4; j++) {
        int col = n0 + wx*64 + j*16 + m16;
        float bj = bias[col];
        float sc = (col < scale_cols) ? 0.125f : 1.0f;
#pragma unroll
        for (int i = 0; i < 2; i++) {
            int rbase = row0 + wy*32 + i*16 + quad*4;
#pragma unroll
            for (int r = 0; r < 4; r++) {
                float v = (acc[i][j][r] + bj) * sc;
                size_t idx = (size_t)(rbase + r)*N + col;
                if (EPI == 0) {
                    ((unsigned short*)Cout)[idx] = f2b(v);
                } else if (EPI == 1) {
                    ((float*)Cout)[idx] = v;
                } else {
                    float gv = 0.5f * v * (1.0f + erff(v * 0.70710678118654752f));
                    ((unsigned short*)Cout)[idx] = f2b(gv);
                }
            }
        }
    }
}

// ---------------------------------------------------------------------------
// Flash attention, transposed-score formulation. No barriers, no LDS (primary).
// S^T = K·Q^T  (C-layout: row=key=quad*4+r, col=q=lane&15) -> per-lane scores
// all belong to ONE q-row -> softmax = in-reg reduce + 2 shuffles.
// P^T regs are exactly the B-operand of mfma_16x16x16 -> PV without LDS.
// QKV: bf16 [B*L][1536] (Q pre-scaled by 1/8); VT: bf16 [B*H][64][SEQ].
// ---------------------------------------------------------------------------
__global__ __launch_bounds__(256) void flash_attn(
    const unsigned short* __restrict__ QKV, const unsigned short* __restrict__ VT,
    const int* __restrict__ mask, unsigned short* __restrict__ O)
{
    const int tid = threadIdx.x, wave = tid >> 6, lane = tid & 63;
    const int quad = lane >> 4, m16 = lane & 15;
    const int bh = blockIdx.y, b = bh >> 3, h = bh & 7;
    const int q0 = blockIdx.x * 64 + wave * 16;

    short8 qf[2];
    {
        const unsigned short* qp = QKV + (size_t)(b*SEQ + q0 + m16)*1536 + h*HEAD_DIM + quad*8;
        qf[0] = *(const short8*)(qp);
        qf[1] = *(const short8*)(qp + 32);
    }

    f32x4 accO[4];
#pragma unroll
    for (int dj = 0; dj < 4; dj++) accO[dj] = (f32x4){0.f,0.f,0.f,0.f};
    float mrun = -1e30f, lrun = 0.f;

    const unsigned short* Kbase = QKV + (size_t)b*SEQ*1536 + 512 + h*HEAD_DIM;
    const unsigned short* Vbase = VT + (size_t)bh*HEAD_DIM*SEQ;
    const int* mbase = mask + b*SEQ;

#if !HAVE_MFMA_K16
    __shared__ __align__(16) unsigned short Pb[4][16*64];
#endif

    for (int key0 = 0; key0 < SEQ; key0 += 64) {
        // S^T tiles: nj-th tile covers keys [key0+nj*16, +16)
        f32x4 st[4];
#pragma unroll
        for (int nj = 0; nj < 4; nj++) {
            const unsigned short* kp = Kbase + (size_t)(key0 + nj*16 + m16)*1536 + quad*8;
            short8 k0 = *(const short8*)kp;
            short8 k1 = *(const short8*)(kp + 32);
            f32x4 c = (f32x4){0.f,0.f,0.f,0.f};
            c = __builtin_amdgcn_mfma_f32_16x16x32_bf16(k0, qf[0], c, 0, 0, 0);
            c = __builtin_amdgcn_mfma_f32_16x16x32_bf16(k1, qf[1], c, 0, 0, 0);
            st[nj] = c;
        }

        float s[4][4];
        float mx = -1e30f;
#pragma unroll
        for (int nj = 0; nj < 4; nj++) {
            int4 mv = *(const int4*)(mbase + key0 + nj*16 + quad*4);
            s[nj][0] = mv.x ? st[nj][0] : -1e9f;
            s[nj][1] = mv.y ? st[nj][1] : -1e9f;
            s[nj][2] = mv.z ? st[nj][2] : -1e9f;
            s[nj][3] = mv.w ? st[nj][3] : -1e9f;
            mx = fmaxf(mx, fmaxf(fmaxf(s[nj][0], s[nj][1]), fmaxf(s[nj][2], s[nj][3])));
        }
        mx = fmaxf(mx, __shfl_xor(mx, 16, 64));
        mx = fmaxf(mx, __shfl_xor(mx, 32, 64));
        float mnew = fmaxf(mrun, mx);
        float alpha = __expf(mrun - mnew);

        float rs = 0.f;
        float p[4][4];
#pragma unroll
        for (int nj = 0; nj < 4; nj++) {
            p[nj][0] = __expf(s[nj][0] - mnew);
            p[nj][1] = __expf(s[nj][1] - mnew);
            p[nj][2] = __expf(s[nj][2] - mnew);
            p[nj][3] = __expf(s[nj][3] - mnew);
            rs += (p[nj][0] + p[nj][1]) + (p[nj][2] + p[nj][3]);
        }
        rs += __shfl_xor(rs, 16, 64);
        rs += __shfl_xor(rs, 32, 64);
        mrun = mnew;
        lrun = lrun * alpha + rs;

#pragma unroll
        for (int dj = 0; dj < 4; dj++) {
            accO[dj][0] *= alpha; accO[dj][1] *= alpha;
            accO[dj][2] *= alpha; accO[dj][3] *= alpha;
        }

#if HAVE_MFMA_K16
        short4_t pb[4];
#pragma unroll
        for (int nj = 0; nj < 4; nj++)
            pb[nj] = (short4_t){(short)f2b(p[nj][0]), (short)f2b(p[nj][1]),
                                (short)f2b(p[nj][2]), (short)f2b(p[nj][3])};
        // O^T += V^T · P^T : A[m=d][k=key]=VT frag, B[n=q][k=key]=pb
#pragma unroll
        for (int nj = 0; nj < 4; nj++)
#pragma unroll
            for (int dj = 0; dj < 4; dj++) {
                const unsigned short* vp = Vbase + (size_t)(dj*16 + m16)*SEQ + key0 + nj*16 + quad*4;
                short4_t av = *(const short4_t*)vp;
                accO[dj] = MFMA_K16(av, pb[nj], accO[dj]);
            }
#else
        // Fallback: wave-private LDS round-trip, P in A-layout [q][key]
#pragma unroll
        for (int nj = 0; nj < 4; nj++)
#pragma unroll
            for (int r = 0; r < 4; r++)
                Pb[wave][m16*64 + nj*16 + quad*4 + r] = f2b(p[nj][r]);
        asm volatile("s_waitcnt lgkmcnt(0)" ::: "memory");
        {
            short8 aP0 = *(const short8*)&Pb[wave][m16*64 + quad*8];
            short8 aP1 = *(const short8*)&Pb[wave][m16*64 + 32 + quad*8];
#pragma unroll
            for (int dj = 0; dj < 4; dj++) {
                const unsigned short* vp = Vbase + (size_t)(dj*16 + m16)*SEQ + key0 + quad*8;
                short8 v0 = *(const short8*)vp;
                short8 v1 = *(const short8*)(vp + 32);
                accO[dj] = __builtin_amdgcn_mfma_f32_16x16x32_bf16(aP0, v0, accO[dj], 0, 0, 0);
                accO[dj] = __builtin_amdgcn_mfma_f32_16x16x32_bf16(aP1, v1, accO[dj], 0, 0, 0);
            }
        }
        asm volatile("s_waitcnt lgkmcnt(0)" ::: "memory");
#endif
    }

    float rl = 1.0f / lrun;
#if HAVE_MFMA_K16
    // O^T C-layout: row=d=quad*4+r, col=q=m16 -> 4 contiguous bf16 per store
#pragma unroll
    for (int dj = 0; dj < 4; dj++) {
        short4_t o;
        o[0] = (short)f2b(accO[dj][0] * rl);
        o[1] = (short)f2b(accO[dj][1] * rl);
        o[2] = (short)f2b(accO[dj][2] * rl);
        o[3] = (short)f2b(accO[dj][3] * rl);
        *(short4_t*)&O[(size_t)(b*SEQ + q0 + m16)*D_EMBED + h*HEAD_DIM + dj*16 + quad*4] = o;
    }
#else
    // O C-layout: row=q=quad*4+r, col=d=m16
#pragma unroll
    for (int r = 0; r < 4; r++)
#pragma unroll
        for (int dj = 0; dj < 4; dj++)
            O[(size_t)(b*SEQ + q0 + quad*4 + r)*D_EMBED + h*HEAD_DIM + dj*16 + m16]
                = f2b(accO[dj][r] * rl);
#endif
}

// ---------------------------------------------------------------------------
// y = LayerNorm(A + B)*g + be -> fp32 Yf (and bf16 Yb if non-null)
// ---------------------------------------------------------------------------
__global__ __launch_bounds__(256) void ln_res(
    const float* __restrict__ A, const float* __restrict__ Bv,
    const float* __restrict__ g, const float* __restrict__ be,
    float* __restrict__ Yf, unsigned short* __restrict__ Yb)
{
    const int wave = threadIdx.x >> 6, lane = threadIdx.x & 63;
    const int row = blockIdx.x * 4 + wave;
    const float* ap = A  + (size_t)row*512 + lane*8;
    const float* bp = Bv + (size_t)row*512 + lane*8;
    float v[8]; float s = 0.f;
#pragma unroll
    for (int j = 0; j < 8; j++) { v[j] = ap[j] + bp[j]; s += v[j]; }
#pragma unroll
    for (int off = 32; off >= 1; off >>= 1) s += __shfl_xor(s, off, 64);
    float mu = s * (1.f/512.f);
    float q = 0.f;
#pragma unroll
    for (int j = 0; j < 8; j++) { v[j] -= mu; q += v[j]*v[j]; }
#pragma unroll
    for (int off = 32; off >= 1; off >>= 1) q += __shfl_xor(q, off, 64);
    float rstd = rsqrtf(q * (1.f/512.f) + 1e-5f);
#pragma unroll
    for (int j = 0; j < 8; j++) {
        float y = v[j]*rstd*g[lane*8+j] + be[lane*8+j];
        if (Yf) Yf[(size_t)row*512 + lane*8 + j] = y;
        if (Yb) Yb[(size_t)row*512 + lane*8 + j] = f2b(y);
    }
}

__global__ __launch_bounds__(256) void cvt_f32_bf16(
    const float* __restrict__ X, unsigned short* __restrict__ Y, int n)
{
    int idx = (blockIdx.x * 256 + threadIdx.x) * 4;
    if (idx < n) {
        float4 v = *(const float4*)(X + idx);
        Y[idx+0] = f2b(v.x); Y[idx+1] = f2b(v.y);
        Y[idx+2] = f2b(v.z); Y[idx+3] = f2b(v.w);
    }
}

// W[K][N] fp32 -> WT[N][K] bf16. block (32,8), grid (N/32, K/32)
__global__ void transpose_w(const float* __restrict__ W, unsigned short* __restrict__ WT,
                            int K, int N)
{
    __shared__ float t[32][33];
    int n0 = blockIdx.x*32, k0 = blockIdx.y*32;
    int x = threadIdx.x, y = threadIdx.y;
#pragma unroll
    for (int yy = y; yy < 32; yy += 8) t[yy][x] = W[(size_t)(k0+yy)*N + n0 + x];
    __syncthreads();
#pragma unroll
    for (int yy = y; yy < 32; yy += 8) WT[(size_t)(n0+yy)*K + k0 + x] = f2b(t[x][yy]);
}

// V (cols 1024..1535 of QKV) -> VT bf16 [B*H][64][SEQ]. grid (SEQ/32, 2, 16)
__global__ void transpose_v(const unsigned short* __restrict__ QKV, unsigned short* __restrict__ VT)
{
    __shared__ unsigned short t[32][33];
    int bh = blockIdx.z, b = bh >> 3, h = bh & 7;
    int l0 = blockIdx.x*32, d0 = blockIdx.y*32;
    int x = threadIdx.x, y = threadIdx.y;
#pragma unroll
    for (int yy = y; yy < 32; yy += 8)
        t[yy][x] = QKV[(size_t)(b*SEQ + l0+yy)*1536 + 1024 + h*64 + d0 + x];
    __syncthreads();
#pragma unroll
    for (int yy = y; yy < 32; yy += 8)
        VT[((size_t)bh*64 + d0+yy)*SEQ + l0 + x] = t[x][yy];
}

__global__ void concat3(const float* __restrict__ a, const float* __restrict__ b,
                        const float* __restrict__ c, float* __restrict__ o)
{
    int i = blockIdx.x*256 + threadIdx.x;  // 1536 total
    o[i] = (i < 512) ? a[i] : ((i < 1024) ? b[i-512] : c[i-1024]);
}

extern "C" void kernel_launch(void* const* d_in, const int* in_sizes, int n_in,
                              void* d_out, int out_size, void* d_ws, size_t ws_size,
                              hipStream_t stream)
{
    const float* x    = (const float*)d_in[0];
    const int*   mask = (const int*)  d_in[1];
    const float* Wq = (const float*)d_in[2];  const float* bq = (const float*)d_in[3];
    const float* Wk = (const float*)d_in[4];  const float* bk = (const float*)d_in[5];
    const float* Wv = (const float*)d_in[6];  const float* bv = (const float*)d_in[7];
    const float* Wo = (const float*)d_in[8];  const float* bo = (const float*)d_in[9];
    const float* ln1g = (const float*)d_in[10]; const float* ln1b = (const float*)d_in[11];
    const float* ln2g = (const float*)d_in[12]; const float* ln2b = (const float*)d_in[13];
    const float* W1 = (const float*)d_in[14]; const float* b1 = (const float*)d_in[15];
    const float* W2 = (const float*)d_in[16]; const float* b2 = (const float*)d_in[17];
    float* out = (float*)d_out;

    char* ws = (char*)d_ws;
    const size_t MB = 1024*1024;
    unsigned short* xb    = (unsigned short*)(ws + 0);           // 8 MB (reused as hb later)
    unsigned short* WqkvT = (unsigned short*)(ws + 8*MB);        // 1.5 MB [1536][512]
    unsigned short* W1T   = (unsigned short*)(ws + 10*MB);       // 2 MB
    unsigned short* W2T   = (unsigned short*)(ws + 12*MB);       // 2 MB
    unsigned short* WoT   = (unsigned short*)(ws + 14*MB);       // 0.5 MB
    float*          bqkv  = (float*)(ws + 14*MB + 512*1024);     // 6 KB
    unsigned short* QKVb  = (unsigned short*)(ws + 15*MB);       // 24 MB [8192][1536]
    unsigned short* VTb   = (unsigned short*)(ws + 39*MB);       // 8 MB
    unsigned short* ctx   = (unsigned short*)(ws + 47*MB);       // 8 MB
    float*          atf   = (float*)(ws + 55*MB);                // 16 MB
    float*          hf    = (float*)(ws + 71*MB);                // 16 MB (peak 87 MB)
    unsigned short* hb    = (unsigned short*)(ws + 0);           // overlays dead xb
    unsigned short* Gb    = (unsigned short*)(ws + 15*MB);       // 32 MB, overlays QKV/VT
    float*          ff    = (float*)(ws + 47*MB);                // 16 MB, overlays ctx/atf

    dim3 tb(32, 8);
    cvt_f32_bf16<<<4096, 256, 0, stream>>>(x, xb, M_ROWS*D_EMBED);
    transpose_w<<<dim3(16,16), tb, 0, stream>>>(Wq, WqkvT,            512, 512);
    transpose_w<<<dim3(16,16), tb, 0, stream>>>(Wk, WqkvT + 512*512,  512, 512);
    transpose_w<<<dim3(16,16), tb, 0, stream>>>(Wv, WqkvT + 1024*512, 512, 512);
    transpose_w<<<dim3(16,16), tb, 0, stream>>>(Wo, WoT, 512, 512);
    transpose_w<<<dim3(64,16), tb, 0, stream>>>(W1, W1T, 512, 2048);
    transpose_w<<<dim3(16,64), tb, 0, stream>>>(W2, W2T, 2048, 512);
    concat3<<<6, 256, 0, stream>>>(bq, bk, bv, bqkv);

    // fused QKV projection, Q pre-scaled by 1/8
    gemm_bt<0><<<dim3(12,64), 256, 0, stream>>>(xb, WqkvT, bqkv, QKVb, M_ROWS, 1536, 512, 512);

    transpose_v<<<dim3(SEQ/32, 2, 16), tb, 0, stream>>>(QKVb, VTb);
    flash_attn<<<dim3(SEQ/64, 16), 256, 0, stream>>>(QKVb, VTb, mask, ctx);

    gemm_bt64<1><<<dim3(4,128), 256, 0, stream>>>(ctx, WoT, bo, atf, M_ROWS, 512, 512, 0);
    ln_res<<<M_ROWS/4, 256, 0, stream>>>(x, atf, ln1g, ln1b, hf, hb);

    gemm_bt<2><<<dim3(16,64), 256, 0, stream>>>(hb, W1T, b1, Gb, M_ROWS, D_FF, 512, 0);
    gemm_bt64<1><<<dim3(4,128), 256, 0, stream>>>(Gb, W2T, b2, ff, M_ROWS, 512, D_FF, 0);
    ln_res<<<M_ROWS/4, 256, 0, stream>>>(hf, ff, ln2g, ln2b, out, (unsigned short*)nullptr);
}